// Round 3
// baseline (2567.053 us; speedup 1.0000x reference)
//
#include <hip/hip_runtime.h>

// BjorckLinear: out = X @ bjorck10(W)^T
//   X: [131072, 512] f32, W: [512, 512] f32, out: [131072, 512] f32
//
// R3: (a) entire Bjorck phase fused into ONE kernel with software grid
//     barriers (512 blocks, residency guaranteed via __launch_bounds__(256,2):
//     ~80 VGPR + 2KB LDS => 2 blocks/CU capacity >= grid);
//     (b) k_big: double-buffered LDS, global_load_lds(w16) for W with
//     XOR-swizzle (pre-swizzled source + swizzled ds_read), reg-staged X
//     with convert-at-stage, stage(k+1) overlapped with compute(k).

using bf16x8 = __attribute__((ext_vector_type(8))) short;
using f32x4  = __attribute__((ext_vector_type(4))) float;
using u16x8  = __attribute__((ext_vector_type(8))) unsigned short;

#define DI 512
#define NBLK 512   // blocks in fused Bjorck kernel

__device__ __forceinline__ unsigned short f2bf(float f) {
  unsigned int u = __builtin_bit_cast(unsigned int, f);
  u += 0x7FFFu + ((u >> 16) & 1u);   // RNE
  return (unsigned short)(u >> 16);
}
__device__ __forceinline__ float bf2f(unsigned short h) {
  unsigned int u = ((unsigned int)h) << 16;
  return __builtin_bit_cast(float, u);
}

// ---------------- software grid barrier (device-scope) ----------------
__device__ __forceinline__ void grid_barrier(int* cnt, int* gen) {
  __threadfence();            // release: flush this wave's writes (L2 wb)
  __syncthreads();            // all waves of block fenced
  if (threadIdx.x == 0) {
    int g = __hip_atomic_load(gen, __ATOMIC_ACQUIRE, __HIP_MEMORY_SCOPE_AGENT);
    if (__hip_atomic_fetch_add(cnt, 1, __ATOMIC_ACQ_REL, __HIP_MEMORY_SCOPE_AGENT) == NBLK - 1) {
      __hip_atomic_store(cnt, 0, __ATOMIC_RELAXED, __HIP_MEMORY_SCOPE_AGENT);
      __hip_atomic_fetch_add(gen, 1, __ATOMIC_ACQ_REL, __HIP_MEMORY_SCOPE_AGENT);
    } else {
      while (__hip_atomic_load(gen, __ATOMIC_ACQUIRE, __HIP_MEMORY_SCOPE_AGENT) == g)
        __builtin_amdgcn_s_sleep(4);
    }
  }
  __syncthreads();
  __threadfence();            // acquire: invalidate stale L1/L2 lines
}

struct BP {
  float *Wm0, *Wm1;
  unsigned short *Wh0, *Wl0, *WTh0, *WTl0;
  unsigned short *Wh1, *Wl1, *WTh1, *WTl1;
  unsigned short *Gh, *Gl;
  int *cnt, *gen;
  const float* W;
};

// ---------------- fused Bjorck: split + 10 x (gram, update) ----------------
__global__ __launch_bounds__(256, 2) void k_bjorck(BP p) {
  // phase -1: split W -> f32 master + hi/lo bf16 (+ transposed)
  {
    int base = blockIdx.x * 256 + threadIdx.x;
#pragma unroll
    for (int r = 0; r < 2; ++r) {
      int idx = base + r * (NBLK * 256);
      int m = idx >> 9, i = idx & 511;
      float w = p.W[idx];
      p.Wm0[idx] = w;
      unsigned short h = f2bf(w), lo = f2bf(w - bf2f(h));
      p.Wh0[idx] = h; p.Wl0[idx] = lo;
      p.WTh0[i * DI + m] = h; p.WTl0[i * DI + m] = lo;
    }
  }
  grid_barrier(p.cnt, p.gen);

  const int tid = threadIdx.x;
  const int l = tid & 63, lw = tid >> 6;
  const int wid = blockIdx.x * 4 + lw;        // 0..2047
  const int tile = wid >> 1, half = wid & 1;  // 1024 tiles, 2-way K-split
  const int m0 = (tile >> 5) << 4, n0 = (tile & 31) << 4;
  const int kb = half << 8;                   // K half: 0 or 256
  const int lm = l & 15, lk = l >> 4;
  const int ra0 = (m0 + lm) * DI + kb + (lk << 3);
  const int rb0 = (n0 + lm) * DI + kb + (lk << 3);

  __shared__ f32x4 red[2][64];
  const int pr = lw >> 1;

  float *Wm_c = p.Wm0, *Wm_n = p.Wm1;
  unsigned short *Wh_c = p.Wh0, *Wl_c = p.Wl0, *WTh_c = p.WTh0, *WTl_c = p.WTl0;
  unsigned short *Wh_n = p.Wh1, *Wl_n = p.Wl1, *WTh_n = p.WTh1, *WTl_n = p.WTl1;

  for (int it = 0; it < 10; ++it) {
    // ---- gram: G = W^T W  (NT product of WT with itself, 3-term split) ----
    {
      f32x4 a0{}, a1{}, a2{}, a3{}, a4{}, a5{};
#pragma unroll
      for (int k0 = 0; k0 < 256; k0 += 64) {
        bf16x8 ah0 = *(const bf16x8*)&WTh_c[ra0 + k0];
        bf16x8 al0 = *(const bf16x8*)&WTl_c[ra0 + k0];
        bf16x8 bh0 = *(const bf16x8*)&WTh_c[rb0 + k0];
        bf16x8 bl0 = *(const bf16x8*)&WTl_c[rb0 + k0];
        bf16x8 ah1 = *(const bf16x8*)&WTh_c[ra0 + k0 + 32];
        bf16x8 al1 = *(const bf16x8*)&WTl_c[ra0 + k0 + 32];
        bf16x8 bh1 = *(const bf16x8*)&WTh_c[rb0 + k0 + 32];
        bf16x8 bl1 = *(const bf16x8*)&WTl_c[rb0 + k0 + 32];
        a0 = __builtin_amdgcn_mfma_f32_16x16x32_bf16(ah0, bh0, a0, 0, 0, 0);
        a1 = __builtin_amdgcn_mfma_f32_16x16x32_bf16(ah0, bl0, a1, 0, 0, 0);
        a2 = __builtin_amdgcn_mfma_f32_16x16x32_bf16(al0, bh0, a2, 0, 0, 0);
        a3 = __builtin_amdgcn_mfma_f32_16x16x32_bf16(ah1, bh1, a3, 0, 0, 0);
        a4 = __builtin_amdgcn_mfma_f32_16x16x32_bf16(ah1, bl1, a4, 0, 0, 0);
        a5 = __builtin_amdgcn_mfma_f32_16x16x32_bf16(al1, bh1, a5, 0, 0, 0);
      }
      f32x4 acc = (a0 + a1) + (a2 + a3) + (a4 + a5);
      if (half) red[pr][l] = acc;
      __syncthreads();
      if (!half) {
        acc += red[pr][l];
        const int gr0 = m0 + (lk << 2);
#pragma unroll
        for (int r = 0; r < 4; ++r) {
          float v = acc[r];
          unsigned short h = f2bf(v);
          p.Gh[(gr0 + r) * DI + n0 + lm] = h;
          p.Gl[(gr0 + r) * DI + n0 + lm] = f2bf(v - bf2f(h));
        }
      }
    }
    grid_barrier(p.cnt, p.gen);
    // ---- update: Wn = 1.5 Wc - 0.5 Wc G  (G symmetric => NT with B=G) ----
    {
      f32x4 a0{}, a1{}, a2{}, a3{}, a4{}, a5{};
#pragma unroll
      for (int k0 = 0; k0 < 256; k0 += 64) {
        bf16x8 ah0 = *(const bf16x8*)&Wh_c[ra0 + k0];
        bf16x8 al0 = *(const bf16x8*)&Wl_c[ra0 + k0];
        bf16x8 bh0 = *(const bf16x8*)&p.Gh[rb0 + k0];
        bf16x8 bl0 = *(const bf16x8*)&p.Gl[rb0 + k0];
        bf16x8 ah1 = *(const bf16x8*)&Wh_c[ra0 + k0 + 32];
        bf16x8 al1 = *(const bf16x8*)&Wl_c[ra0 + k0 + 32];
        bf16x8 bh1 = *(const bf16x8*)&p.Gh[rb0 + k0 + 32];
        bf16x8 bl1 = *(const bf16x8*)&p.Gl[rb0 + k0 + 32];
        a0 = __builtin_amdgcn_mfma_f32_16x16x32_bf16(ah0, bh0, a0, 0, 0, 0);
        a1 = __builtin_amdgcn_mfma_f32_16x16x32_bf16(ah0, bl0, a1, 0, 0, 0);
        a2 = __builtin_amdgcn_mfma_f32_16x16x32_bf16(al0, bh0, a2, 0, 0, 0);
        a3 = __builtin_amdgcn_mfma_f32_16x16x32_bf16(ah1, bh1, a3, 0, 0, 0);
        a4 = __builtin_amdgcn_mfma_f32_16x16x32_bf16(ah1, bl1, a4, 0, 0, 0);
        a5 = __builtin_amdgcn_mfma_f32_16x16x32_bf16(al1, bh1, a5, 0, 0, 0);
      }
      f32x4 acc = (a0 + a1) + (a2 + a3) + (a4 + a5);
      if (half) red[pr][l] = acc;
      __syncthreads();
      if (!half) {
        acc += red[pr][l];
        const int gr0 = m0 + (lk << 2);
#pragma unroll
        for (int r = 0; r < 4; ++r) {
          const int gm = gr0 + r, gn = n0 + lm;
          const float wn = 1.5f * Wm_c[gm * DI + gn] - 0.5f * acc[r];
          Wm_n[gm * DI + gn] = wn;
          unsigned short h = f2bf(wn), lo = f2bf(wn - bf2f(h));
          Wh_n[gm * DI + gn] = h;   Wl_n[gm * DI + gn] = lo;
          WTh_n[gn * DI + gm] = h;  WTl_n[gn * DI + gm] = lo;
        }
      }
    }
    grid_barrier(p.cnt, p.gen);
    // swap ping-pong sets
    { float* t = Wm_c; Wm_c = Wm_n; Wm_n = t; }
    { unsigned short* t;
      t = Wh_c;  Wh_c = Wh_n;   Wh_n = t;
      t = Wl_c;  Wl_c = Wl_n;   Wl_n = t;
      t = WTh_c; WTh_c = WTh_n; WTh_n = t;
      t = WTl_c; WTl_c = WTl_n; WTl_n = t; }
  }
}

// ---------------- direct-to-LDS helper ----------------
#if defined(__has_builtin)
#if __has_builtin(__builtin_amdgcn_global_load_lds)
#define HAVE_GLDS 1
#endif
#endif

#ifdef HAVE_GLDS
__device__ __forceinline__ void gl2lds16(const unsigned short* g, unsigned short* lds) {
  __builtin_amdgcn_global_load_lds(
      (const __attribute__((address_space(1))) void*)g,
      (__attribute__((address_space(3))) void*)lds, 16, 0, 0);
}
#endif

// ---------------- big GEMM: out = bf16(X) @ Wp^T ----------------
// grid 2048, block 256 (4 waves), BM=64, BN=512 (X read once), BK=32.
// LDS double-buffered; W staged via global_load_lds w16 with XOR-swizzled
// source; X reg-staged (load f32 -> cvt bf16 -> swizzled ds_write).
// Swizzle (16B chunk units, 4/row): stored chunk = c ^ ((row>>1)&3)  => all
// LDS reads/writes spread 64 lanes uniformly over 32 banks (2/bank = free).
__global__ __launch_bounds__(256, 2) void k_big(
    const float* __restrict__ X, const unsigned short* __restrict__ Wp,
    float* __restrict__ out) {
  __shared__ unsigned short sA[2][2048];    // 64 rows x 32 k, 4 KB each
  __shared__ unsigned short sB[2][16384];   // 512 rows x 32 k, 32 KB each
  const int tid = threadIdx.x;
  const int w = tid >> 6, l = tid & 63;
  const int lm = l & 15, lk = l >> 4;
  const int ck = lk ^ ((lm >> 1) & 3);      // swizzled read chunk
  const int rowbase = blockIdx.x << 6;

  // X staging coords (thread t: row t>>2, chunk t&3)
  const int arow = tid >> 2, ac = tid & 3;
  const int alds = (arow * 4 + (ac ^ ((arow >> 1) & 3))) * 8;
  const float* xsrc = &X[(rowbase + arow) * DI + ac * 8];

  // B staging coords: s((l>>2)) = (l>>3)&3 since rowblk % 8 == 0
  const int brow_l = l >> 2;
  const int bcs = (l & 3) ^ ((brow_l >> 1) & 3);

  f32x4 acc[4][8] = {};

  auto stage_b = [&](int kk, int bb) {
#pragma unroll
    for (int ph = 0; ph < 8; ++ph) {
      const int rowblk = ph * 64 + w * 16;
      const unsigned short* src = &Wp[(rowblk + brow_l) * DI + (kk << 5) + bcs * 8];
#ifdef HAVE_GLDS
      gl2lds16(src, &sB[bb][rowblk * 32]);
#else
      u16x8 v = *(const u16x8*)src;
      *(u16x8*)&sB[bb][rowblk * 32 + l * 8] = v;
#endif
    }
  };

  // prologue: stage k=0
  f32x4 xv0 = *(const f32x4*)xsrc;
  f32x4 xv1 = *(const f32x4*)(xsrc + 4);
  stage_b(0, 0);
  {
    u16x8 h;
    h[0] = f2bf(xv0[0]); h[1] = f2bf(xv0[1]); h[2] = f2bf(xv0[2]); h[3] = f2bf(xv0[3]);
    h[4] = f2bf(xv1[0]); h[5] = f2bf(xv1[1]); h[6] = f2bf(xv1[2]); h[7] = f2bf(xv1[3]);
    *(u16x8*)&sA[0][alds] = h;
  }
  __syncthreads();

  for (int k = 0; k < 16; ++k) {
    const int buf = k & 1;
    if (k < 15) {                       // issue next-tile loads first
      xv0 = *(const f32x4*)(xsrc + ((k + 1) << 5));
      xv1 = *(const f32x4*)(xsrc + ((k + 1) << 5) + 4);
      stage_b(k + 1, buf ^ 1);
    }
    // compute current tile
    bf16x8 a[4], b[8];
#pragma unroll
    for (int mf = 0; mf < 4; ++mf)
      a[mf] = *(const bf16x8*)&sA[buf][((mf * 16 + lm) * 4 + ck) * 8];
#pragma unroll
    for (int nf = 0; nf < 8; ++nf)
      b[nf] = *(const bf16x8*)&sB[buf][((w * 128 + nf * 16 + lm) * 4 + ck) * 8];
#pragma unroll
    for (int mf = 0; mf < 4; ++mf)
#pragma unroll
      for (int nf = 0; nf < 8; ++nf)
        acc[mf][nf] = __builtin_amdgcn_mfma_f32_16x16x32_bf16(a[mf], b[nf], acc[mf][nf], 0, 0, 0);
    if (k < 15) {                       // convert + write next A tile
      u16x8 h;
      h[0] = f2bf(xv0[0]); h[1] = f2bf(xv0[1]); h[2] = f2bf(xv0[2]); h[3] = f2bf(xv0[3]);
      h[4] = f2bf(xv1[0]); h[5] = f2bf(xv1[1]); h[6] = f2bf(xv1[2]); h[7] = f2bf(xv1[3]);
      *(u16x8*)&sA[buf ^ 1][alds] = h;
    }
    __syncthreads();
  }

  const int cn = lm;
#pragma unroll
  for (int mf = 0; mf < 4; ++mf) {
    const int r0 = rowbase + (mf << 4) + (lk << 2);
#pragma unroll
    for (int nf = 0; nf < 8; ++nf) {
      const int col = (w << 7) + (nf << 4) + cn;
#pragma unroll
      for (int r = 0; r < 4; ++r)
        out[(r0 + r) * DI + col] = acc[mf][nf][r];
    }
  }
}

extern "C" void kernel_launch(void* const* d_in, const int* in_sizes, int n_in,
                              void* d_out, int out_size, void* d_ws, size_t ws_size,
                              hipStream_t stream) {
  const float* X = (const float*)d_in[0];
  const float* W = (const float*)d_in[1];
  float* out = (float*)d_out;

  char* ws = (char*)d_ws;
  size_t off = 0;
  auto carve = [&](size_t bytes) { void* p = ws + off; off += (bytes + 255) & ~(size_t)255; return p; };

  const size_t F32 = (size_t)DI * DI * 4;
  const size_t BF  = (size_t)DI * DI * 2;

  BP p;
  p.Wm0  = (float*)carve(F32);          p.Wm1  = (float*)carve(F32);
  p.Wh0  = (unsigned short*)carve(BF);  p.Wh1  = (unsigned short*)carve(BF);
  p.Wl0  = (unsigned short*)carve(BF);  p.Wl1  = (unsigned short*)carve(BF);
  p.WTh0 = (unsigned short*)carve(BF);  p.WTh1 = (unsigned short*)carve(BF);
  p.WTl0 = (unsigned short*)carve(BF);  p.WTl1 = (unsigned short*)carve(BF);
  p.Gh   = (unsigned short*)carve(BF);
  p.Gl   = (unsigned short*)carve(BF);
  int* bar = (int*)carve(256);
  p.cnt = bar; p.gen = bar + 32;
  p.W = W;

  hipMemsetAsync(bar, 0, 256, stream);           // reset barrier state each call
  k_bjorck<<<NBLK, 256, 0, stream>>>(p);         // split + 10 iterations fused
  k_big<<<2048, 256, 0, stream>>>(X, p.Wh0, out);  // 10 flips -> final in set 0
}

// Round 4
// 391.246 us; speedup vs baseline: 6.5612x; 6.5612x over previous
//
#include <hip/hip_runtime.h>

// BjorckLinear: out = X @ bjorck10(W)^T
//   X: [131072, 512] f32, W: [512, 512] f32, out: [131072, 512] f32
//
// R4: grid-barrier fusion reverted (cross-XCD fence storm: 2.4ms). Back to
// 21 launches. New: (a) k_mm2 2-way K-split (2048 waves, 4-deep K chain);
// (b) k_big epilogue via swapped MFMA operands -> D[n][m] -> each lane holds
// 4 consecutive output columns -> global_store_dwordx4 (was 128 scalar stores).

using bf16x8 = __attribute__((ext_vector_type(8))) short;
using f32x4  = __attribute__((ext_vector_type(4))) float;
using u16x8  = __attribute__((ext_vector_type(8))) unsigned short;

#define DI 512

__device__ __forceinline__ unsigned short f2bf(float f) {
  unsigned int u = __builtin_bit_cast(unsigned int, f);
  u += 0x7FFFu + ((u >> 16) & 1u);   // RNE
  return (unsigned short)(u >> 16);
}
__device__ __forceinline__ float bf2f(unsigned short h) {
  unsigned int u = ((unsigned int)h) << 16;
  return __builtin_bit_cast(float, u);
}

// ---- initial split: W f32 -> f32 master + hi/lo bf16 (+ transposed) ----
__global__ void k_split(const float* __restrict__ W, float* __restrict__ Wm,
                        unsigned short* __restrict__ Wh, unsigned short* __restrict__ Wl,
                        unsigned short* __restrict__ WTh, unsigned short* __restrict__ WTl) {
  int idx = blockIdx.x * blockDim.x + threadIdx.x;
  int m = idx >> 9, i = idx & 511;
  float w = W[idx];
  Wm[idx] = w;
  unsigned short h  = f2bf(w);
  unsigned short lo = f2bf(w - bf2f(h));
  Wh[idx] = h; Wl[idx] = lo;
  WTh[i * DI + m] = h; WTl[i * DI + m] = lo;
}

// ---- 512x512 NT GEMM: wave per (16x16 tile, K-half); LDS pair-reduce ----
// C[m][n] = sum_k A'[m][k] * B'[n][k]  (A'=Ah+Al, B'=Bh+Bl; l*l dropped)
// mode 0 (gram):   C -> hi/lo bf16 (Oh, Ol)
// mode 1 (update): Wnew = 1.5*Wm_in - 0.5*C -> f32 + hi/lo + transposed hi/lo
__global__ __launch_bounds__(256) void k_mm2(
    const unsigned short* __restrict__ Ah, const unsigned short* __restrict__ Al,
    const unsigned short* __restrict__ Bh, const unsigned short* __restrict__ Bl,
    int mode,
    const float* __restrict__ Wm_in, float* __restrict__ Wm_out,
    unsigned short* __restrict__ Oh, unsigned short* __restrict__ Ol,
    unsigned short* __restrict__ OTh, unsigned short* __restrict__ OTl) {
  const int tid = threadIdx.x;
  const int l = tid & 63, lw = tid >> 6;
  const int wid = (blockIdx.x << 2) | lw;     // 0..2047
  const int tile = wid >> 1, half = wid & 1;  // 1024 tiles x 2 K-halves
  const int m0 = (tile >> 5) << 4, n0 = (tile & 31) << 4;
  const int kb = half << 8;
  const int lm = l & 15, lk = l >> 4;
  const int ra = (m0 + lm) * DI + kb + (lk << 3);
  const int rb = (n0 + lm) * DI + kb + (lk << 3);

  __shared__ f32x4 red[2][64];
  const int pr = lw >> 1;

  f32x4 a0{}, a1{}, a2{}, a3{}, a4{}, a5{};
#pragma unroll
  for (int k0 = 0; k0 < 256; k0 += 64) {
    bf16x8 ah0 = *(const bf16x8*)&Ah[ra + k0];
    bf16x8 al0 = *(const bf16x8*)&Al[ra + k0];
    bf16x8 bh0 = *(const bf16x8*)&Bh[rb + k0];
    bf16x8 bl0 = *(const bf16x8*)&Bl[rb + k0];
    bf16x8 ah1 = *(const bf16x8*)&Ah[ra + k0 + 32];
    bf16x8 al1 = *(const bf16x8*)&Al[ra + k0 + 32];
    bf16x8 bh1 = *(const bf16x8*)&Bh[rb + k0 + 32];
    bf16x8 bl1 = *(const bf16x8*)&Bl[rb + k0 + 32];
    a0 = __builtin_amdgcn_mfma_f32_16x16x32_bf16(ah0, bh0, a0, 0, 0, 0);
    a1 = __builtin_amdgcn_mfma_f32_16x16x32_bf16(ah0, bl0, a1, 0, 0, 0);
    a2 = __builtin_amdgcn_mfma_f32_16x16x32_bf16(al0, bh0, a2, 0, 0, 0);
    a3 = __builtin_amdgcn_mfma_f32_16x16x32_bf16(ah1, bh1, a3, 0, 0, 0);
    a4 = __builtin_amdgcn_mfma_f32_16x16x32_bf16(ah1, bl1, a4, 0, 0, 0);
    a5 = __builtin_amdgcn_mfma_f32_16x16x32_bf16(al1, bh1, a5, 0, 0, 0);
  }
  f32x4 acc = (a0 + a1) + (a2 + a3) + (a4 + a5);

  if (half) red[pr][l] = acc;
  __syncthreads();
  if (!half) {
    acc += red[pr][l];
    const int r0 = m0 + (lk << 2);
    const int cn = n0 + lm;
#pragma unroll
    for (int r = 0; r < 4; ++r) {
      const int gm = r0 + r, gn = cn;
      const float v = acc[r];
      if (mode == 0) {
        unsigned short h = f2bf(v);
        Oh[gm * DI + gn] = h;
        Ol[gm * DI + gn] = f2bf(v - bf2f(h));
      } else {
        const float wn = 1.5f * Wm_in[gm * DI + gn] - 0.5f * v;
        Wm_out[gm * DI + gn] = wn;
        unsigned short h = f2bf(wn), lo = f2bf(wn - bf2f(h));
        Oh[gm * DI + gn] = h;   Ol[gm * DI + gn] = lo;
        OTh[gn * DI + gm] = h;  OTl[gn * DI + gm] = lo;
      }
    }
  }
}

// ---------------- direct-to-LDS helper ----------------
#if defined(__has_builtin)
#if __has_builtin(__builtin_amdgcn_global_load_lds)
#define HAVE_GLDS 1
#endif
#endif

#ifdef HAVE_GLDS
__device__ __forceinline__ void gl2lds16(const unsigned short* g, unsigned short* lds) {
  __builtin_amdgcn_global_load_lds(
      (const __attribute__((address_space(1))) void*)g,
      (__attribute__((address_space(3))) void*)lds, 16, 0, 0);
}
#endif

// ---------------- big GEMM: out = bf16(X) @ Wp^T ----------------
// grid 2048, block 256 (4 waves), BM=64, BN=512 (X read once), BK=32.
// Double-buffered LDS; W via global_load_lds w16 (pre-swizzled source);
// X reg-staged (f32 -> bf16 cvt -> swizzled ds_write). Stage(k+1) issued
// before compute(k). MFMA operands SWAPPED: D = W_frag x X_frag^T = out^T
// fragment => lane holds out[m][n..n+3] -> dwordx4 stores.
__global__ __launch_bounds__(256, 2) void k_big(
    const float* __restrict__ X, const unsigned short* __restrict__ Wp,
    float* __restrict__ out) {
  __shared__ unsigned short sA[2][2048];    // 64 rows x 32 k
  __shared__ unsigned short sB[2][16384];   // 512 rows x 32 k
  const int tid = threadIdx.x;
  const int w = tid >> 6, l = tid & 63;
  const int lm = l & 15, lk = l >> 4;
  const int ck = lk ^ ((lm >> 1) & 3);      // swizzled read chunk
  const int rowbase = blockIdx.x << 6;

  // X staging coords (thread t: row t>>2, chunk t&3)
  const int arow = tid >> 2, ac = tid & 3;
  const int alds = (arow * 4 + (ac ^ ((arow >> 1) & 3))) * 8;
  const float* xsrc = &X[(rowbase + arow) * DI + ac * 8];

  // B staging: lane covers row l>>2 of a 16-row block; source chunk swizzled
  const int brow_l = l >> 2;
  const int bcs = (l & 3) ^ ((brow_l >> 1) & 3);

  f32x4 acc[4][8] = {};

  auto stage_b = [&](int kk, int bb) {
#pragma unroll
    for (int ph = 0; ph < 8; ++ph) {
      const int rowblk = ph * 64 + w * 16;
      const unsigned short* src = &Wp[(rowblk + brow_l) * DI + (kk << 5) + bcs * 8];
#ifdef HAVE_GLDS
      gl2lds16(src, &sB[bb][rowblk * 32]);
#else
      u16x8 v = *(const u16x8*)src;
      *(u16x8*)&sB[bb][rowblk * 32 + l * 8] = v;
#endif
    }
  };

  // prologue: stage k=0
  f32x4 xv0 = *(const f32x4*)xsrc;
  f32x4 xv1 = *(const f32x4*)(xsrc + 4);
  stage_b(0, 0);
  {
    u16x8 h;
    h[0] = f2bf(xv0[0]); h[1] = f2bf(xv0[1]); h[2] = f2bf(xv0[2]); h[3] = f2bf(xv0[3]);
    h[4] = f2bf(xv1[0]); h[5] = f2bf(xv1[1]); h[6] = f2bf(xv1[2]); h[7] = f2bf(xv1[3]);
    *(u16x8*)&sA[0][alds] = h;
  }
  __syncthreads();

  for (int k = 0; k < 16; ++k) {
    const int buf = k & 1;
    if (k < 15) {                       // issue next-tile loads first
      xv0 = *(const f32x4*)(xsrc + ((k + 1) << 5));
      xv1 = *(const f32x4*)(xsrc + ((k + 1) << 5) + 4);
      stage_b(k + 1, buf ^ 1);
    }
    bf16x8 a[4], b[8];
#pragma unroll
    for (int mf = 0; mf < 4; ++mf)
      a[mf] = *(const bf16x8*)&sA[buf][((mf * 16 + lm) * 4 + ck) * 8];
#pragma unroll
    for (int nf = 0; nf < 8; ++nf)
      b[nf] = *(const bf16x8*)&sB[buf][((w * 128 + nf * 16 + lm) * 4 + ck) * 8];
    // swapped operands: acc[mf][nf] = D[n-rows][m-cols]
#pragma unroll
    for (int mf = 0; mf < 4; ++mf)
#pragma unroll
      for (int nf = 0; nf < 8; ++nf)
        acc[mf][nf] = __builtin_amdgcn_mfma_f32_16x16x32_bf16(b[nf], a[mf], acc[mf][nf], 0, 0, 0);
    if (k < 15) {
      u16x8 h;
      h[0] = f2bf(xv0[0]); h[1] = f2bf(xv0[1]); h[2] = f2bf(xv0[2]); h[3] = f2bf(xv0[3]);
      h[4] = f2bf(xv1[0]); h[5] = f2bf(xv1[1]); h[6] = f2bf(xv1[2]); h[7] = f2bf(xv1[3]);
      *(u16x8*)&sA[buf ^ 1][alds] = h;
    }
    __syncthreads();
  }

  // epilogue: lane holds out[gm][gn..gn+3] per (mf,nf) -> dwordx4 stores
#pragma unroll
  for (int mf = 0; mf < 4; ++mf) {
    const int gm = rowbase + (mf << 4) + lm;
#pragma unroll
    for (int nf = 0; nf < 8; ++nf) {
      const int gn = (w << 7) + (nf << 4) + (lk << 2);
      *(f32x4*)&out[gm * DI + gn] = acc[mf][nf];
    }
  }
}

extern "C" void kernel_launch(void* const* d_in, const int* in_sizes, int n_in,
                              void* d_out, int out_size, void* d_ws, size_t ws_size,
                              hipStream_t stream) {
  const float* X = (const float*)d_in[0];
  const float* W = (const float*)d_in[1];
  float* out = (float*)d_out;

  char* ws = (char*)d_ws;
  size_t off = 0;
  auto carve = [&](size_t bytes) { void* p = ws + off; off += (bytes + 255) & ~(size_t)255; return p; };

  const size_t F32 = (size_t)DI * DI * 4;
  const size_t BF  = (size_t)DI * DI * 2;

  float* Wm[2];           unsigned short *Wh[2], *Wl[2], *WTh[2], *WTl[2];
  Wm[0]  = (float*)carve(F32);          Wm[1]  = (float*)carve(F32);
  Wh[0]  = (unsigned short*)carve(BF);  Wh[1]  = (unsigned short*)carve(BF);
  Wl[0]  = (unsigned short*)carve(BF);  Wl[1]  = (unsigned short*)carve(BF);
  WTh[0] = (unsigned short*)carve(BF);  WTh[1] = (unsigned short*)carve(BF);
  WTl[0] = (unsigned short*)carve(BF);  WTl[1] = (unsigned short*)carve(BF);
  unsigned short* Gh = (unsigned short*)carve(BF);
  unsigned short* Gl = (unsigned short*)carve(BF);

  k_split<<<1024, 256, 0, stream>>>(W, Wm[0], Wh[0], Wl[0], WTh[0], WTl[0]);

  int cur = 0;
  for (int it = 0; it < 10; ++it) {
    // G = W^T W  (NT on transposed-W arrays)
    k_mm2<<<512, 256, 0, stream>>>(WTh[cur], WTl[cur], WTh[cur], WTl[cur], 0,
                                   nullptr, nullptr, Gh, Gl, nullptr, nullptr);
    const int nxt = cur ^ 1;
    // Wnew = 1.5 W - 0.5 W G   (G symmetric)
    k_mm2<<<512, 256, 0, stream>>>(Wh[cur], Wl[cur], Gh, Gl, 1,
                                   Wm[cur], Wm[nxt], Wh[nxt], Wl[nxt], WTh[nxt], WTl[nxt]);
    cur = nxt;
  }

  k_big<<<2048, 256, 0, stream>>>(X, Wh[cur], out);
}